// Round 15
// baseline (88.790 us; speedup 1.0000x reference)
//
#include <hip/hip_runtime.h>
#include <hip/hip_bf16.h>
#include <stdint.h>

// Problem constants
#define NB    32    // batch
#define CIN   128
#define HH    56
#define WW    56
#define COUT  256
#define HP    58    // padded height (H+2)
#define WP    64    // padded width (56+2 -> padded to 64)

// ws layout: xp (bf16, NB*HP*WP*CIN) then wpack (bf16, 36*8192)
#define XP_ELEMS   (NB * HP * WP * CIN)

typedef __attribute__((ext_vector_type(4))) float f32x4;
typedef __attribute__((ext_vector_type(8))) short bf16x8;

__device__ __forceinline__ unsigned short f2bf(float f) {
    union { float f; unsigned u; } v; v.f = f;
    unsigned r = v.u + 0x7FFFu + ((v.u >> 16) & 1u);
    return (unsigned short)(r >> 16);
}

__device__ __forceinline__ void gload16(const void* g, void* l) {
    __builtin_amdgcn_global_load_lds(
        (__attribute__((address_space(1))) void*)(void*)g,
        (__attribute__((address_space(3))) void*)l,
        16, 0, 0);
}

// ---------------------------------------------------------------------------
// Fused prep: blocks [0,256) compose weights; blocks [256,256+HP*NB) pack x.
//
// wpack layout (R13-verified): [tile(36)][wid(4)][mf(4)][lane(64)][kin(8)]
//   elem = tile*8192 + wid*2048 + mf*512 + lane*8 + kin; tile = pos*4+cib,
//   o = wid*64+mf*16+fl, lane = kpos*16+fl, ci = cib*32+kpos*8+kin.
// xp layout (R14-verified): [b][ih][ch(16)][iw(64)][kin(8)], ch = ci>>3.
// ---------------------------------------------------------------------------
__global__ __launch_bounds__(256) void prep(
    const float* __restrict__ x, const float* __restrict__ dict,
    const float* __restrict__ coef, const int* __restrict__ idxw,
    unsigned short* __restrict__ wpack, unsigned short* __restrict__ xp) {
    int tid = threadIdx.x;

    if (blockIdx.x < COUT) {
        // ---- build_weight ----
        int o = blockIdx.x;
        bool mode64 = (idxw[1] == 0) && (idxw[3] == 0) && (idxw[5] == 0) &&
                      (idxw[7] == 0) && (idxw[9] == 0) && (idxw[11] == 0) &&
                      (idxw[13] == 0) && (idxw[15] == 0);
        float c[8]; int di[8];
#pragma unroll
        for (int s = 0; s < 8; ++s) {
            c[s]  = coef[o * 8 + s];
            di[s] = mode64 ? idxw[(o * 8 + s) * 2] : idxw[o * 8 + s];
        }
        const int wid = o >> 6, mf = (o >> 4) & 3, fl = o & 15;
        for (int j = tid; j < 9 * 128; j += 256) {
            int pos = j >> 7;          // 0..8
            int ci  = j & 127;
            int kh = pos / 3, kw = pos - kh * 3;
            float v = 0.f;
#pragma unroll
            for (int s = 0; s < 8; ++s)
                v += c[s] * dict[((di[s] * CIN + ci) * 3 + kh) * 3 + kw];
            int tile = pos * 4 + (ci >> 5);
            int kpos = (ci >> 3) & 3, kin = ci & 7;
            wpack[tile * 8192 + wid * 2048 + mf * 512 + (kpos * 16 + fl) * 8 + kin]
                = f2bf(v);
        }
        return;
    }

    // ---- pack_x: NCHW fp32 -> zero-padded [ch][iw][kin] bf16 ----
    int idx = blockIdx.x - COUT;
    int ih = idx % HP;         // 0..57
    int b  = idx / HP;         // 0..31
    size_t obase = ((size_t)(b * HP + ih)) * WP * CIN;
    bf16x8* outv = (bf16x8*)(xp + obase);   // 1024 vectors: index = ch*64 + iw

    if (ih == 0 || ih == HP - 1) {
        bf16x8 z = {0, 0, 0, 0, 0, 0, 0, 0};
        for (int e = tid; e < WP * CIN / 8; e += 256) outv[e] = z;
        return;
    }

    __shared__ float xs[CIN][WW + 1];   // +1 pad: odd stride
    int h = ih - 1;
    for (int e = tid; e < CIN * WW; e += 256) {
        int ci = e / WW, w = e - ci * WW;
        xs[ci][w] = x[(((size_t)b * CIN + ci) * HH + h) * WW + w];
    }
    __syncthreads();
    for (int e = tid; e < WP * CIN / 8; e += 256) {
        int iw = e & 63;             // fast-varying -> coalesced stores
        int cb = (e >> 6) << 3;      // ci base
        bf16x8 v = {0, 0, 0, 0, 0, 0, 0, 0};
        if (iw >= 1 && iw <= WW) {
#pragma unroll
            for (int j = 0; j < 8; ++j)
                v[j] = (short)f2bf(xs[cb + j][iw - 1]);
        }
        outv[e] = v;
    }
}

// ---------------------------------------------------------------------------
// Main: implicit-GEMM conv, RESIDENT-B / ZERO-K-LOOP-BARRIER (R14-verified)
// + R15: ping-pong A-fragment sets, NO register rotation.
//   R14 post-mortem: the afc<-afn 16-mov rotation forced s_waitcnt vmcnt(0)
//   ~80 cyc after the afn issue (L2 ~200-300 cyc) -> per-step stall. With
//   ping-pong af[(cib+pos)&1] the wait happens at next-step USE as a counted
//   vmcnt(4), a full ~630-cyc step after issue. #pragma unroll 2 on cib
//   makes (cib+pos)&1 compile-time static (rule #20: no dynamic indexing).
//  - Block = 256 threads = 4 waves = 256 Cout x ONE output row; slab
//    rows oh..oh+2 staged once; ONE barrier per block.
//  - (256,3): 3 blocks/CU by LDS (49.4 KB); ~96 arch + 64 AGPR regs.
// ---------------------------------------------------------------------------
__global__ __launch_bounds__(256, 3) void conv_mfma(
    const unsigned short* __restrict__ xp,
    const unsigned short* __restrict__ wpack,
    float* __restrict__ out) {
    // slab: elem = ((row*16 + ch)*64 + iw)*8 + kin; +128 pad for junk-col reads
    __shared__ unsigned short Bl[3 * 16 * 64 * 8 + 128];

    int tid  = threadIdx.x;
    int lane = tid & 63;
    int wid  = tid >> 6;       // 0..3 = Cout slice of 64

    // XCD-bijective swizzle: 1792 = 8 * 224; each XCD gets 4 consecutive b's
    int flat = blockIdx.x;
    int swz  = (flat & 7) * 224 + (flat >> 3);
    int b    = swz / 56;       // 0..31
    int oh   = swz % 56;       // output row

    const int klane = lane >> 4;   // k-group (0..3)
    const int fl    = lane & 15;

    f32x4 acc[4][4];
    f32x4 zero = {0.f, 0.f, 0.f, 0.f};
#pragma unroll
    for (int i = 0; i < 4; ++i)
#pragma unroll
        for (int j = 0; j < 4; ++j) acc[i][j] = zero;

    // A-fragment base (coalesced): af(tile,mf) = ap0 + tile*8192 + mf*512 elems
    const unsigned short* ap0 = wpack + (size_t)wid * 2048 + lane * 8;

    // ---- prologue: stage 3-row slab (48 slices of 1 KB, linear copy) ----
    const unsigned short* xrow = xp + ((size_t)(b * HP + oh)) * 8192;
#pragma unroll
    for (int j = 0; j < 12; ++j) {
        int s = wid + j * 4;           // 0..47 = row*16 + ch
        gload16(xrow + (size_t)(s >> 4) * 8192 + (s & 15) * 512 + lane * 8,
                &Bl[s * 512]);
    }

    bf16x8 af[2][4];
#pragma unroll
    for (int mf = 0; mf < 4; ++mf)
        af[0][mf] = *(const bf16x8*)(ap0 + mf * 512);
    __syncthreads();   // slab resident; ONLY barrier in the kernel

    const unsigned short* apc = ap0;                       // += 8192/cib
    const unsigned short* bl0 = &Bl[klane * 512 + fl * 8];

#pragma unroll 2
    for (int cib = 0; cib < 4; ++cib) {
        const unsigned short* bcur = bl0 + cib * 2048;

#pragma unroll
        for (int pos = 0; pos < 9; ++pos) {
            const int kh = pos / 3, kw = pos - kh * 3;
            const int cur = (cib + pos) & 1;   // STATIC under unroll-2 cib

            // ---- prefetch A(next step) into the free set (ping-pong) ----
            if (pos < 8) {
#pragma unroll
                for (int mf = 0; mf < 4; ++mf)
                    af[cur ^ 1][mf] =
                        *(const bf16x8*)(apc + (pos + 1) * 32768 + mf * 512);
            } else if (cib < 3) {
#pragma unroll
                for (int mf = 0; mf < 4; ++mf)
                    af[cur ^ 1][mf] = *(const bf16x8*)(apc + 8192 + mf * 512);
            }

            // ---- B fragments from resident slab (imm-offset ds_read) ----
            bf16x8 bfr[4];
#pragma unroll
            for (int nf = 0; nf < 4; ++nf)
                bfr[nf] = *(const bf16x8*)(bcur + kh * 8192 + (nf * 16 + kw) * 8);

            // ---- 16 MFMA on af[cur] (loaded a full step ago) ----
            __builtin_amdgcn_s_setprio(1);
#pragma unroll
            for (int mf = 0; mf < 4; ++mf)
#pragma unroll
                for (int nf = 0; nf < 4; ++nf)
                    acc[mf][nf] = __builtin_amdgcn_mfma_f32_16x16x32_bf16(
                        af[cur][mf], bfr[nf], acc[mf][nf], 0, 0, 0);
            __builtin_amdgcn_s_setprio(0);
        }
        apc += 8192;
    }

    // Epilogue: C/D layout col = lane&15, row = (lane>>4)*4 + reg (m89-verified)
#pragma unroll
    for (int nf = 0; nf < 4; ++nf) {
        int ow = nf * 16 + fl;
        if (ow < WW) {
#pragma unroll
            for (int mf = 0; mf < 4; ++mf) {
                int ob = wid * 64 + mf * 16 + (lane >> 4) * 4;
                float* dst = out + (((size_t)b * COUT + ob) * HH + oh) * WW + ow;
#pragma unroll
                for (int r = 0; r < 4; ++r)
                    dst[(size_t)r * HH * WW] = acc[mf][nf][r];
            }
        }
    }
}

extern "C" void kernel_launch(void* const* d_in, const int* in_sizes, int n_in,
                              void* d_out, int out_size, void* d_ws, size_t ws_size,
                              hipStream_t stream) {
    const float* x    = (const float*)d_in[0];
    const float* dict = (const float*)d_in[1];
    const float* coef = (const float*)d_in[2];
    const int*   idxw = (const int*)d_in[3];
    float* out = (float*)d_out;

    unsigned short* xp    = (unsigned short*)d_ws;
    unsigned short* wpack = xp + XP_ELEMS;

    prep<<<dim3(COUT + HP * NB), dim3(256), 0, stream>>>(x, dict, coef, idxw, wpack, xp);
    conv_mfma<<<dim3(NB * 56), dim3(256), 0, stream>>>(xp, wpack, out);
}

// Round 16
// 82.380 us; speedup vs baseline: 1.0778x; 1.0778x over previous
//
#include <hip/hip_runtime.h>
#include <hip/hip_bf16.h>
#include <stdint.h>

// Problem constants
#define NB    32    // batch
#define CIN   128
#define HH    56
#define WW    56
#define COUT  256

// ws layout: wpack only (bf16, 36*8192 = 294,912 elems)
typedef __attribute__((ext_vector_type(4))) float f32x4;
typedef __attribute__((ext_vector_type(8))) short bf16x8;

__device__ __forceinline__ unsigned short f2bf(float f) {
    union { float f; unsigned u; } v; v.f = f;
    unsigned r = v.u + 0x7FFFu + ((v.u >> 16) & 1u);
    return (unsigned short)(r >> 16);
}

// ---------------------------------------------------------------------------
// build_weight: compose per-output-channel filters.
// wpack layout (R13-verified): [tile(36)][wid(4)][mf(4)][lane(64)][kin(8)]
//   elem = tile*8192 + wid*2048 + mf*512 + lane*8 + kin; tile = pos*4+cib,
//   o = wid*64+mf*16+fl, lane = kpos*16+fl, ci = cib*32+kpos*8+kin.
// ---------------------------------------------------------------------------
__global__ __launch_bounds__(256) void build_weight(
    const float* __restrict__ dict, const float* __restrict__ coef,
    const int* __restrict__ idxw, unsigned short* __restrict__ wpack) {
    int o = blockIdx.x;
    int tid = threadIdx.x;
    bool mode64 = (idxw[1] == 0) && (idxw[3] == 0) && (idxw[5] == 0) &&
                  (idxw[7] == 0) && (idxw[9] == 0) && (idxw[11] == 0) &&
                  (idxw[13] == 0) && (idxw[15] == 0);
    float c[8]; int di[8];
#pragma unroll
    for (int s = 0; s < 8; ++s) {
        c[s]  = coef[o * 8 + s];
        di[s] = mode64 ? idxw[(o * 8 + s) * 2] : idxw[o * 8 + s];
    }
    const int wid = o >> 6, mf = (o >> 4) & 3, fl = o & 15;
    for (int j = tid; j < 9 * 128; j += 256) {
        int pos = j >> 7;          // 0..8
        int ci  = j & 127;
        int kh = pos / 3, kw = pos - kh * 3;
        float v = 0.f;
#pragma unroll
        for (int s = 0; s < 8; ++s)
            v += c[s] * dict[((di[s] * CIN + ci) * 3 + kh) * 3 + kw];
        int tile = pos * 4 + (ci >> 5);
        int kpos = (ci >> 3) & 3, kin = ci & 7;
        wpack[tile * 8192 + wid * 2048 + mf * 512 + (kpos * 16 + fl) * 8 + kin]
            = f2bf(v);
    }
}

// ---------------------------------------------------------------------------
// Main: FUSED pack + implicit-GEMM conv (R16).
// R15 post-mortem: conv pinned at ~67us across 5 scheduling variants; the
// real remaining fat was the 16us serial prep stage. Each block now packs
// its OWN 3-row slab directly from fp32 NCHW x (86 KB, ~2/3 L2-hit since
// adjacent-oh blocks share rows), eliminating the xp intermediate entirely.
//
// Slab layout: [row(3)][ch(16)][iw(64)][kin(8)] with ch-stride PADDED to
// 520 elems (1040 B): bank offset +4 per ch -> transposed pack writes are
// bank-conflict-free (worst 2-way aliasing = free, m136), and main-loop
// reads keep compile-time imm offsets (verified pattern, 0 conflicts).
//
// Pack: threads 0..191 = (row, ci-pair); 2 half-chunks of 28 w (<=56 VGPR
// live -> total unified ~154 < 170 at (256,3): no spill, R3/R5 lesson).
// Threads 192..239 zero the pad columns (iw=0, 57..63).
// Main loop/epilogue = R15 verbatim (strides 512->520 etc).
// ---------------------------------------------------------------------------
__global__ __launch_bounds__(256, 3) void conv_mfma(
    const float* __restrict__ x,
    const unsigned short* __restrict__ wpack,
    float* __restrict__ out) {
    // slab: elem = (row*16 + ch)*520 + iw*8 + kin ; +16 tail pad (junk reads)
    __shared__ unsigned short Bl[3 * 16 * 520 + 16];

    int tid  = threadIdx.x;
    int lane = tid & 63;
    int wid  = tid >> 6;       // 0..3 = Cout slice of 64

    // XCD-bijective swizzle: 1792 = 8 * 224; each XCD gets 4 consecutive b's
    int flat = blockIdx.x;
    int swz  = (flat & 7) * 224 + (flat >> 3);
    int b    = swz / 56;       // 0..31
    int oh   = swz % 56;       // output row

    const int klane = lane >> 4;   // k-group (0..3)
    const int fl    = lane & 15;

    // A-fragment base (coalesced): af(tile,mf) = ap0 + tile*8192 + mf*512 elems
    const unsigned short* ap0 = wpack + (size_t)wid * 2048 + lane * 8;

    // ---- issue A(tile 0) early: latency hides under the pack phase ----
    bf16x8 af[2][4];
#pragma unroll
    for (int mf = 0; mf < 4; ++mf)
        af[0][mf] = *(const bf16x8*)(ap0 + mf * 512);

    // ---- pack phase: x (fp32 NCHW) -> LDS slab (bf16, transposed) ----
    if (tid < 192) {
        int row = tid >> 6;        // 0..2
        int cp  = tid & 63;        // ci-pair
        int ci0 = cp << 1;
        int ch  = ci0 >> 3;        // 0..15
        int koff = ci0 & 7;        // 0,2,4,6
        int h = oh + row - 1;      // x row; -1/56 => zero pad row
        bool valid = (h >= 0) && (h < HH);
        const f32x4* pa = (const f32x4*)(x + (((size_t)b * CIN + ci0) * HH + h) * WW);
        const f32x4* pb = (const f32x4*)(x + (((size_t)b * CIN + ci0 + 1) * HH + h) * WW);
        unsigned char* wb = (unsigned char*)&Bl[(row * 16 + ch) * 520 + koff];
#pragma unroll
        for (int half = 0; half < 2; ++half) {
            f32x4 va[7], vb[7];
            if (valid) {
#pragma unroll
                for (int j = 0; j < 7; ++j) va[j] = pa[half * 7 + j];
#pragma unroll
                for (int j = 0; j < 7; ++j) vb[j] = pb[half * 7 + j];
            } else {
#pragma unroll
                for (int j = 0; j < 7; ++j) {
                    va[j] = (f32x4){0.f, 0.f, 0.f, 0.f};
                    vb[j] = (f32x4){0.f, 0.f, 0.f, 0.f};
                }
            }
#pragma unroll
            for (int w7 = 0; w7 < 28; ++w7) {
                int w = half * 28 + w7;            // compile-time
                unsigned pv = (unsigned)f2bf(va[w7 >> 2][w7 & 3]) |
                              ((unsigned)f2bf(vb[w7 >> 2][w7 & 3]) << 16);
                *(unsigned*)(wb + (w + 1) * 16) = pv;   // iw = w+1
            }
        }
    } else if (tid < 240) {
        int v = tid - 192;         // 0..47 = (row, ch)
        int row = v >> 4, ch = v & 15;
        bf16x8 z = {0, 0, 0, 0, 0, 0, 0, 0};
        unsigned short* zb = &Bl[(row * 16 + ch) * 520];
        *(bf16x8*)zb = z;                          // iw = 0 (left pad)
#pragma unroll
        for (int iw = 57; iw < 64; ++iw)           // right pad + junk
            *(bf16x8*)(zb + iw * 8) = z;
    }

    f32x4 acc[4][4];
    f32x4 zero = {0.f, 0.f, 0.f, 0.f};
#pragma unroll
    for (int i = 0; i < 4; ++i)
#pragma unroll
        for (int j = 0; j < 4; ++j) acc[i][j] = zero;

    __syncthreads();   // slab resident; ONLY barrier in the kernel

    const unsigned short* apc = ap0;                       // += 8192/cib
    const unsigned short* bl0 = &Bl[klane * 520 + fl * 8];

#pragma unroll 2
    for (int cib = 0; cib < 4; ++cib) {
        const unsigned short* bcur = bl0 + cib * 2080;     // 4 ch per cib

#pragma unroll
        for (int pos = 0; pos < 9; ++pos) {
            const int kh = pos / 3, kw = pos - kh * 3;
            const int cur = (cib + pos) & 1;   // STATIC under unroll-2 cib

            // ---- prefetch A(next step) into the free set (ping-pong) ----
            if (pos < 8) {
#pragma unroll
                for (int mf = 0; mf < 4; ++mf)
                    af[cur ^ 1][mf] =
                        *(const bf16x8*)(apc + (pos + 1) * 32768 + mf * 512);
            } else if (cib < 3) {
#pragma unroll
                for (int mf = 0; mf < 4; ++mf)
                    af[cur ^ 1][mf] = *(const bf16x8*)(apc + 8192 + mf * 512);
            }

            // ---- B fragments from resident slab (imm-offset ds_read) ----
            bf16x8 bfr[4];
#pragma unroll
            for (int nf = 0; nf < 4; ++nf)
                bfr[nf] = *(const bf16x8*)(bcur + kh * 8320 + (nf * 16 + kw) * 8);

            // ---- 16 MFMA on af[cur] (loaded a full step ago) ----
            __builtin_amdgcn_s_setprio(1);
#pragma unroll
            for (int mf = 0; mf < 4; ++mf)
#pragma unroll
                for (int nf = 0; nf < 4; ++nf)
                    acc[mf][nf] = __builtin_amdgcn_mfma_f32_16x16x32_bf16(
                        af[cur][mf], bfr[nf], acc[mf][nf], 0, 0, 0);
            __builtin_amdgcn_s_setprio(0);
        }
        apc += 8192;
    }

    // Epilogue: C/D layout col = lane&15, row = (lane>>4)*4 + reg (m89-verified)
#pragma unroll
    for (int nf = 0; nf < 4; ++nf) {
        int ow = nf * 16 + fl;
        if (ow < WW) {
#pragma unroll
            for (int mf = 0; mf < 4; ++mf) {
                int ob = wid * 64 + mf * 16 + (lane >> 4) * 4;
                float* dst = out + (((size_t)b * COUT + ob) * HH + oh) * WW + ow;
#pragma unroll
                for (int r = 0; r < 4; ++r)
                    dst[(size_t)r * HH * WW] = acc[mf][nf][r];
            }
        }
    }
}

extern "C" void kernel_launch(void* const* d_in, const int* in_sizes, int n_in,
                              void* d_out, int out_size, void* d_ws, size_t ws_size,
                              hipStream_t stream) {
    const float* x    = (const float*)d_in[0];
    const float* dict = (const float*)d_in[1];
    const float* coef = (const float*)d_in[2];
    const int*   idxw = (const int*)d_in[3];
    float* out = (float*)d_out;

    unsigned short* wpack = (unsigned short*)d_ws;

    build_weight<<<dim3(COUT), dim3(256), 0, stream>>>(dict, coef, idxw, wpack);
    conv_mfma<<<dim3(NB * 56), dim3(256), 0, stream>>>(x, wpack, out);
}